// Round 8
// baseline (5875.711 us; speedup 1.0000x reference)
//
#include <hip/hip_runtime.h>

typedef __attribute__((ext_vector_type(2))) _Float16 half2_t;

#define NJ 7
#define HID 4

// ---- ws layout (u32 slots) ----
// [0..47]    WIHJ: 12 gates x 4 half2 (pre-scaled: g<8 by -log2e, g>=8 by 2*log2e)
// [48..71]   WHHJ: 12 gates x 2 half2 (same scaling)
// [72..95]   WIHM: 12 x 2 half2
// [96..119]  WHHM: 12 x 2 half2
// [120..127] BSUMJ rz: 8 f32   ((bih+bhh)*-log2e)
// [128..131] BIHJ_n: 4 f32     (*2log2e)
// [132..135] BHHJ_n: 4 f32     (*2log2e)
// [136..143] BSUMM rz: 8 f32
// [144..147] BIHM_n: 4 f32
// [148..151] BHHM_n: 4 f32

__device__ __forceinline__ half2_t h2(unsigned int u) {
    return __builtin_bit_cast(half2_t, u);
}
// EXPERIMENT r8: v_fma_mix_f32 path instead of v_dot2_f32_f16.
// fmaf((float)f16, (float)f16, f32) folds to a single v_fma_mix_f32 (full-rate),
// testing the hypothesis that v_dot2_f32_f16 issues at quarter rate.
__device__ __forceinline__ float fdot2f(half2_t a, half2_t b, float c) {
    float r = fmaf((float)a.x, (float)b.x, c);
    return fmaf((float)a.y, (float)b.y, r);
}
__device__ __forceinline__ half2_t pk(float a, float b) {
    return __builtin_bit_cast(half2_t, __builtin_amdgcn_cvt_pkrtz(a, b));
}

__global__ __launch_bounds__(256) void prep_kernel(
    const float* __restrict__ Wih_j, const float* __restrict__ Whh_j,
    const float* __restrict__ bih_j, const float* __restrict__ bhh_j,
    const float* __restrict__ Wih_m, const float* __restrict__ Whh_m,
    const float* __restrict__ bih_m, const float* __restrict__ bhh_m,
    unsigned int* __restrict__ ws)
{
    const float c1 = -1.44269504f;  // -log2(e): r,z gates
    const float c2 = 2.88539008f;   // 2*log2(e): n gates
    int t = threadIdx.x;
    if (t < 48) {                       // WIHJ
        int g = t >> 2, k = t & 3;
        float s = (g < 8) ? c1 : c2;
        ws[t] = __builtin_bit_cast(unsigned int,
                    pk(Wih_j[g*8 + 2*k] * s, Wih_j[g*8 + 2*k + 1] * s));
    } else if (t < 72) {                // WHHJ
        int i = t - 48; int g = i >> 1, k = i & 1;
        float s = (g < 8) ? c1 : c2;
        ws[t] = __builtin_bit_cast(unsigned int,
                    pk(Whh_j[g*4 + 2*k] * s, Whh_j[g*4 + 2*k + 1] * s));
    } else if (t < 96) {                // WIHM
        int i = t - 72; int g = i >> 1, k = i & 1;
        float s = (g < 8) ? c1 : c2;
        ws[t] = __builtin_bit_cast(unsigned int,
                    pk(Wih_m[g*4 + 2*k] * s, Wih_m[g*4 + 2*k + 1] * s));
    } else if (t < 120) {               // WHHM
        int i = t - 96; int g = i >> 1, k = i & 1;
        float s = (g < 8) ? c1 : c2;
        ws[t] = __builtin_bit_cast(unsigned int,
                    pk(Whh_m[g*4 + 2*k] * s, Whh_m[g*4 + 2*k + 1] * s));
    } else if (t < 128) {               // BSUMJ rz
        int g = t - 120;
        ws[t] = __float_as_uint((bih_j[g] + bhh_j[g]) * c1);
    } else if (t < 132) {               // BIHJ_n
        int i = t - 128;
        ws[t] = __float_as_uint(bih_j[8 + i] * c2);
    } else if (t < 136) {               // BHHJ_n
        int i = t - 132;
        ws[t] = __float_as_uint(bhh_j[8 + i] * c2);
    } else if (t < 144) {               // BSUMM rz
        int g = t - 136;
        ws[t] = __float_as_uint((bih_m[g] + bhh_m[g]) * c1);
    } else if (t < 148) {               // BIHM_n
        int i = t - 144;
        ws[t] = __float_as_uint(bih_m[8 + i] * c2);
    } else if (t < 152) {               // BHHM_n
        int i = t - 148;
        ws[t] = __float_as_uint(bhh_m[8 + i] * c2);
    }
}

__global__ __launch_bounds__(256, 4) void aggreg_kernel(
    const float* __restrict__ x,
    const float* __restrict__ Wj,   const float* __restrict__ bj,
    const float* __restrict__ Wm,   const float* __restrict__ bm,
    const float* __restrict__ Wact, const float* __restrict__ bact,
    const unsigned int* __restrict__ wu,
    float* __restrict__ out, int B)
{
    int row = blockIdx.x * blockDim.x + threadIdx.x;
    if (row >= B) return;

    // ---- vectorized x load (19 f32 = 4x float4 + 3) ----
    const float* xp = x + (size_t)row * 19;
    float4 v0 = *(const float4*)(xp + 0);
    float4 v1 = *(const float4*)(xp + 4);
    float4 v2 = *(const float4*)(xp + 8);
    float4 v3 = *(const float4*)(xp + 12);
    float xr[19] = { v0.x, v0.y, v0.z, v0.w,  v1.x, v1.y, v1.z, v1.w,
                     v2.x, v2.y, v2.z, v2.w,  v3.x, v3.y, v3.z, v3.w,
                     xp[16], xp[17], xp[18] };

    // h_j init: jcat (7,2) @ Wj.T + bj ; h_m init: obs (5) @ Wm.T + bm
    float hj[NJ][HID], hm[HID];
    #pragma unroll
    for (int t = 0; t < NJ; ++t)
        #pragma unroll
        for (int o = 0; o < HID; ++o)
            hj[t][o] = bj[o] + Wj[o*2+0]*xr[5+t] + Wj[o*2+1]*xr[12+t];
    #pragma unroll
    for (int o = 0; o < HID; ++o) {
        float a = bm[o];
        #pragma unroll
        for (int k = 0; k < 5; ++k) a += Wm[o*5+k]*xr[k];
        hm[o] = a;
    }

    // ---- bias hoist (as in r6 build) ----
    float bsJ[8], biJ[4], bhJ[4], bsM[8], biM[4], bhM[4];
    #pragma unroll
    for (int g = 0; g < 8; ++g) {
        bsJ[g] = __uint_as_float(wu[120 + g]);  asm volatile("" : "+v"(bsJ[g]));
        bsM[g] = __uint_as_float(wu[136 + g]);  asm volatile("" : "+v"(bsM[g]));
    }
    #pragma unroll
    for (int i = 0; i < 4; ++i) {
        biJ[i] = __uint_as_float(wu[128 + i]);  asm volatile("" : "+v"(biJ[i]));
        bhJ[i] = __uint_as_float(wu[132 + i]);  asm volatile("" : "+v"(bhJ[i]));
        biM[i] = __uint_as_float(wu[144 + i]);  asm volatile("" : "+v"(biM[i]));
        bhM[i] = __uint_as_float(wu[148 + i]);  asm volatile("" : "+v"(bhM[i]));
    }

    for (int it = 0; it < 7; ++it) {
        // snapshot of OLD states, packed to half2 (all cross-unit reads use these)
        half2_t hjp[NJ][2], hmp[2];
        #pragma unroll
        for (int t = 0; t < NJ; ++t) {
            hjp[t][0] = pk(hj[t][0], hj[t][1]);
            hjp[t][1] = pk(hj[t][2], hj[t][3]);
        }
        hmp[0] = pk(hm[0], hm[1]);
        hmp[1] = pk(hm[2], hm[3]);

        // ---- m-GRU: input hj[0] (old pack), hidden hm; in-place update ----
        {
            float mrz[8];
            #pragma unroll
            for (int g = 0; g < 8; ++g) {
                float a = bsM[g];
                a = fdot2f(h2(wu[72 + g*2 + 0]), hjp[0][0], a);
                a = fdot2f(h2(wu[72 + g*2 + 1]), hjp[0][1], a);
                a = fdot2f(h2(wu[96 + g*2 + 0]), hmp[0], a);
                a = fdot2f(h2(wu[96 + g*2 + 1]), hmp[1], a);
                mrz[g] = a;
            }
            #pragma unroll
            for (int i = 0; i < 4; ++i) {
                int gn = 8 + i;
                float gi = biM[i];
                gi = fdot2f(h2(wu[72 + gn*2 + 0]), hjp[0][0], gi);
                gi = fdot2f(h2(wu[72 + gn*2 + 1]), hjp[0][1], gi);
                float gh = bhM[i];
                gh = fdot2f(h2(wu[96 + gn*2 + 0]), hmp[0], gh);
                gh = fdot2f(h2(wu[96 + gn*2 + 1]), hmp[1], gh);
                float r = __builtin_amdgcn_rcpf(1.0f + __builtin_amdgcn_exp2f(mrz[i]));
                float z = __builtin_amdgcn_rcpf(1.0f + __builtin_amdgcn_exp2f(mrz[4+i]));
                float v = gi + r * gh;
                float n = 1.0f - 2.0f * __builtin_amdgcn_rcpf(__builtin_amdgcn_exp2f(v) + 1.0f);
                hm[i] = n + z * (hm[i] - n);   // in-place: joints read hmp (old)
            }
        }

        // ---- joint GRUs: all inputs from old packs; in-place update ----
        #pragma unroll
        for (int t = 0; t < NJ; ++t) {
            half2_t in0 = (t == 0) ? hmp[0] : hjp[t-1][0];
            half2_t in1 = (t == 0) ? hmp[1] : hjp[t-1][1];
            float rz[8];
            #pragma unroll
            for (int g = 0; g < 8; ++g) {
                float a = bsJ[g];
                a = fdot2f(h2(wu[g*4 + 0]), in0, a);
                a = fdot2f(h2(wu[g*4 + 1]), in1, a);
                if (t < 6) {
                    a = fdot2f(h2(wu[g*4 + 2]), hjp[t+1][0], a);
                    a = fdot2f(h2(wu[g*4 + 3]), hjp[t+1][1], a);
                }
                a = fdot2f(h2(wu[48 + g*2 + 0]), hjp[t][0], a);
                a = fdot2f(h2(wu[48 + g*2 + 1]), hjp[t][1], a);
                rz[g] = a;
            }
            #pragma unroll
            for (int i = 0; i < 4; ++i) {
                int gn = 8 + i;
                float gi = biJ[i];
                gi = fdot2f(h2(wu[gn*4 + 0]), in0, gi);
                gi = fdot2f(h2(wu[gn*4 + 1]), in1, gi);
                if (t < 6) {
                    gi = fdot2f(h2(wu[gn*4 + 2]), hjp[t+1][0], gi);
                    gi = fdot2f(h2(wu[gn*4 + 3]), hjp[t+1][1], gi);
                }
                float gh = bhJ[i];
                gh = fdot2f(h2(wu[48 + gn*2 + 0]), hjp[t][0], gh);
                gh = fdot2f(h2(wu[48 + gn*2 + 1]), hjp[t][1], gh);
                float r = __builtin_amdgcn_rcpf(1.0f + __builtin_amdgcn_exp2f(rz[i]));
                float z = __builtin_amdgcn_rcpf(1.0f + __builtin_amdgcn_exp2f(rz[4+i]));
                float v = gi + r * gh;
                float n = 1.0f - 2.0f * __builtin_amdgcn_rcpf(__builtin_amdgcn_exp2f(v) + 1.0f);
                hj[t][i] = n + z * (hj[t][i] - n);  // in-place: peers read hjp (old)
            }
        }
    }

    float* op = out + (size_t)row * 7;
    #pragma unroll
    for (int t = 0; t < NJ; ++t) {
        float a = bact[0];
        #pragma unroll
        for (int k = 0; k < HID; ++k) a += Wact[k] * hj[t][k];
        op[t] = a;
    }
}

extern "C" void kernel_launch(void* const* d_in, const int* in_sizes, int n_in,
                              void* d_out, int out_size, void* d_ws, size_t ws_size,
                              hipStream_t stream) {
    const float* x      = (const float*)d_in[0];
    const float* Wj     = (const float*)d_in[1];
    const float* bj     = (const float*)d_in[2];
    const float* Wm     = (const float*)d_in[3];
    const float* bm     = (const float*)d_in[4];
    const float* Wih_j  = (const float*)d_in[5];
    const float* Whh_j  = (const float*)d_in[6];
    const float* bih_j  = (const float*)d_in[7];
    const float* bhh_j  = (const float*)d_in[8];
    const float* Wih_m  = (const float*)d_in[9];
    const float* Whh_m  = (const float*)d_in[10];
    const float* bih_m  = (const float*)d_in[11];
    const float* bhh_m  = (const float*)d_in[12];
    const float* Wact   = (const float*)d_in[13];
    const float* bact   = (const float*)d_in[14];
    float* out = (float*)d_out;
    unsigned int* ws = (unsigned int*)d_ws;

    prep_kernel<<<1, 256, 0, stream>>>(Wih_j, Whh_j, bih_j, bhh_j,
                                       Wih_m, Whh_m, bih_m, bhh_m, ws);

    int B = in_sizes[0] / 19;
    const int block = 256;
    const int grid  = (B + block - 1) / block;
    aggreg_kernel<<<grid, block, 0, stream>>>(
        x, Wj, bj, Wm, bm, Wact, bact, ws, out, B);
}

// Round 9
// 654.696 us; speedup vs baseline: 8.9747x; 8.9747x over previous
//
#include <hip/hip_runtime.h>

typedef __attribute__((ext_vector_type(2))) _Float16 half2_t;

#define NJ 7
#define HID 4

// ---- ws layout (u32 slots) ----
// [0..47]    WIHJ: 12 gates x 4 half2 (pre-scaled: g<8 by -log2e, g>=8 by 2*log2e)
// [48..71]   WHHJ: 12 gates x 2 half2 (same scaling)
// [72..95]   WIHM: 12 x 2 half2
// [96..119]  WHHM: 12 x 2 half2
// [120..127] BSUMJ rz: 8 f32   ((bih+bhh)*-log2e)
// [128..131] BIHJ_n: 4 f32     (*2log2e)
// [132..135] BHHJ_n: 4 f32     (*2log2e)
// [136..143] BSUMM rz: 8 f32
// [144..147] BIHM_n: 4 f32
// [148..151] BHHM_n: 4 f32

__device__ __forceinline__ unsigned pku(float a, float b) {
    return __builtin_bit_cast(unsigned, __builtin_amdgcn_cvt_pkrtz(a, b));
}
// dot2 via two v_fma_mix_f32 (full-rate FMA pipe, f16 sources read in-place via
// op_sel, f32 accumulate). No C-level f16->f32 casts => no scratch-trigger temps.
__device__ __forceinline__ float fmix2(unsigned w, unsigned h, float c) {
    float d, e;
    asm("v_fma_mix_f32 %0, %1, %2, %3 op_sel_hi:[1,1,0]"
        : "=v"(d) : "v"(w), "v"(h), "v"(c));
    asm("v_fma_mix_f32 %0, %1, %2, %3 op_sel:[1,1,0] op_sel_hi:[1,1,0]"
        : "=v"(e) : "v"(w), "v"(h), "v"(d));
    return e;
}

__global__ __launch_bounds__(256) void prep_kernel(
    const float* __restrict__ Wih_j, const float* __restrict__ Whh_j,
    const float* __restrict__ bih_j, const float* __restrict__ bhh_j,
    const float* __restrict__ Wih_m, const float* __restrict__ Whh_m,
    const float* __restrict__ bih_m, const float* __restrict__ bhh_m,
    unsigned int* __restrict__ ws)
{
    const float c1 = -1.44269504f;  // -log2(e): r,z gates
    const float c2 = 2.88539008f;   // 2*log2(e): n gates
    int t = threadIdx.x;
    if (t < 48) {                       // WIHJ
        int g = t >> 2, k = t & 3;
        float s = (g < 8) ? c1 : c2;
        ws[t] = pku(Wih_j[g*8 + 2*k] * s, Wih_j[g*8 + 2*k + 1] * s);
    } else if (t < 72) {                // WHHJ
        int i = t - 48; int g = i >> 1, k = i & 1;
        float s = (g < 8) ? c1 : c2;
        ws[t] = pku(Whh_j[g*4 + 2*k] * s, Whh_j[g*4 + 2*k + 1] * s);
    } else if (t < 96) {                // WIHM
        int i = t - 72; int g = i >> 1, k = i & 1;
        float s = (g < 8) ? c1 : c2;
        ws[t] = pku(Wih_m[g*4 + 2*k] * s, Wih_m[g*4 + 2*k + 1] * s);
    } else if (t < 120) {               // WHHM
        int i = t - 96; int g = i >> 1, k = i & 1;
        float s = (g < 8) ? c1 : c2;
        ws[t] = pku(Whh_m[g*4 + 2*k] * s, Whh_m[g*4 + 2*k + 1] * s);
    } else if (t < 128) {               // BSUMJ rz
        int g = t - 120;
        ws[t] = __float_as_uint((bih_j[g] + bhh_j[g]) * c1);
    } else if (t < 132) {               // BIHJ_n
        int i = t - 128;
        ws[t] = __float_as_uint(bih_j[8 + i] * c2);
    } else if (t < 136) {               // BHHJ_n
        int i = t - 132;
        ws[t] = __float_as_uint(bhh_j[8 + i] * c2);
    } else if (t < 144) {               // BSUMM rz
        int g = t - 136;
        ws[t] = __float_as_uint((bih_m[g] + bhh_m[g]) * c1);
    } else if (t < 148) {               // BIHM_n
        int i = t - 144;
        ws[t] = __float_as_uint(bih_m[8 + i] * c2);
    } else if (t < 152) {               // BHHM_n
        int i = t - 148;
        ws[t] = __float_as_uint(bhh_m[8 + i] * c2);
    }
}

__global__ __launch_bounds__(256, 3) void aggreg_kernel(
    const float* __restrict__ x,
    const float* __restrict__ Wj,   const float* __restrict__ bj,
    const float* __restrict__ Wm,   const float* __restrict__ bm,
    const float* __restrict__ Wact, const float* __restrict__ bact,
    const unsigned int* __restrict__ wu,
    float* __restrict__ out, int B)
{
    int row = blockIdx.x * blockDim.x + threadIdx.x;
    if (row >= B) return;

    // ---- vectorized x load ----
    const float* xp = x + (size_t)row * 19;
    float4 v0 = *(const float4*)(xp + 0);
    float4 v1 = *(const float4*)(xp + 4);
    float4 v2 = *(const float4*)(xp + 8);
    float4 v3 = *(const float4*)(xp + 12);
    float xr[19] = { v0.x, v0.y, v0.z, v0.w,  v1.x, v1.y, v1.z, v1.w,
                     v2.x, v2.y, v2.z, v2.w,  v3.x, v3.y, v3.z, v3.w,
                     xp[16], xp[17], xp[18] };

    // init matvecs (fp32, once)
    float hj[NJ][HID], hm[HID];
    #pragma unroll
    for (int t = 0; t < NJ; ++t)
        #pragma unroll
        for (int o = 0; o < HID; ++o)
            hj[t][o] = bj[o] + Wj[o*2+0]*xr[5+t] + Wj[o*2+1]*xr[12+t];
    #pragma unroll
    for (int o = 0; o < HID; ++o) {
        float a = bm[o];
        #pragma unroll
        for (int k = 0; k < 5; ++k) a += Wm[o*5+k]*xr[k];
        hm[o] = a;
    }

    // ---- pin the 72 joint-weight words into VGPRs (used 7x per iter;
    //      VOP3-mix sources then need zero staging in the hot loop) ----
    unsigned wvJ[72];
    #pragma unroll
    for (int i = 0; i < 18; ++i) {
        uint4 q = *(const uint4*)(wu + 4*i);
        wvJ[4*i+0] = q.x; wvJ[4*i+1] = q.y; wvJ[4*i+2] = q.z; wvJ[4*i+3] = q.w;
    }
    #pragma unroll
    for (int i = 0; i < 72; ++i) asm volatile("" : "+v"(wvJ[i]));

    // joint biases pinned (VOP3 src2 wants VGPR)
    float bsJ[8], biJ[4], bhJ[4];
    #pragma unroll
    for (int g = 0; g < 8; ++g) { bsJ[g] = __uint_as_float(wu[120+g]); asm volatile("" : "+v"(bsJ[g])); }
    #pragma unroll
    for (int i = 0; i < 4; ++i) {
        biJ[i] = __uint_as_float(wu[128+i]); asm volatile("" : "+v"(biJ[i]));
        bhJ[i] = __uint_as_float(wu[132+i]); asm volatile("" : "+v"(bhJ[i]));
    }

    for (int it = 0; it < 7; ++it) {
        // snapshot OLD states packed into u32 (f16 pairs)
        unsigned hjp[NJ][2], hmp[2];
        #pragma unroll
        for (int t = 0; t < NJ; ++t) {
            hjp[t][0] = pku(hj[t][0], hj[t][1]);
            hjp[t][1] = pku(hj[t][2], hj[t][3]);
        }
        hmp[0] = pku(hm[0], hm[1]);
        hmp[1] = pku(hm[2], hm[3]);

        // ---- m-GRU (1/8 of work: unpinned operands ok) ----
        {
            float mrz[8];
            #pragma unroll
            for (int g = 0; g < 8; ++g) {
                float a = __uint_as_float(wu[136 + g]);
                a = fmix2(wu[72 + g*2 + 0], hjp[0][0], a);
                a = fmix2(wu[72 + g*2 + 1], hjp[0][1], a);
                a = fmix2(wu[96 + g*2 + 0], hmp[0], a);
                a = fmix2(wu[96 + g*2 + 1], hmp[1], a);
                mrz[g] = a;
            }
            #pragma unroll
            for (int i = 0; i < 4; ++i) {
                int gn = 8 + i;
                float gi = __uint_as_float(wu[144 + i]);
                gi = fmix2(wu[72 + gn*2 + 0], hjp[0][0], gi);
                gi = fmix2(wu[72 + gn*2 + 1], hjp[0][1], gi);
                float gh = __uint_as_float(wu[148 + i]);
                gh = fmix2(wu[96 + gn*2 + 0], hmp[0], gh);
                gh = fmix2(wu[96 + gn*2 + 1], hmp[1], gh);
                float r = __builtin_amdgcn_rcpf(1.0f + __builtin_amdgcn_exp2f(mrz[i]));
                float z = __builtin_amdgcn_rcpf(1.0f + __builtin_amdgcn_exp2f(mrz[4+i]));
                float v = gi + r * gh;
                float n = 1.0f - 2.0f * __builtin_amdgcn_rcpf(__builtin_amdgcn_exp2f(v) + 1.0f);
                hm[i] = n + z * (hm[i] - n);   // in-place: joints read hmp (old)
            }
        }

        // ---- joint GRUs: pinned weights, in-place update ----
        #pragma unroll
        for (int t = 0; t < NJ; ++t) {
            unsigned in0 = (t == 0) ? hmp[0] : hjp[t-1][0];
            unsigned in1 = (t == 0) ? hmp[1] : hjp[t-1][1];
            float rz[8];
            #pragma unroll
            for (int g = 0; g < 8; ++g) {
                float a = bsJ[g];
                a = fmix2(wvJ[g*4 + 0], in0, a);
                a = fmix2(wvJ[g*4 + 1], in1, a);
                if (t < 6) {
                    a = fmix2(wvJ[g*4 + 2], hjp[t+1][0], a);
                    a = fmix2(wvJ[g*4 + 3], hjp[t+1][1], a);
                }
                a = fmix2(wvJ[48 + g*2 + 0], hjp[t][0], a);
                a = fmix2(wvJ[48 + g*2 + 1], hjp[t][1], a);
                rz[g] = a;
            }
            #pragma unroll
            for (int i = 0; i < 4; ++i) {
                int gn = 8 + i;
                float gi = biJ[i];
                gi = fmix2(wvJ[gn*4 + 0], in0, gi);
                gi = fmix2(wvJ[gn*4 + 1], in1, gi);
                if (t < 6) {
                    gi = fmix2(wvJ[gn*4 + 2], hjp[t+1][0], gi);
                    gi = fmix2(wvJ[gn*4 + 3], hjp[t+1][1], gi);
                }
                float gh = bhJ[i];
                gh = fmix2(wvJ[48 + gn*2 + 0], hjp[t][0], gh);
                gh = fmix2(wvJ[48 + gn*2 + 1], hjp[t][1], gh);
                float r = __builtin_amdgcn_rcpf(1.0f + __builtin_amdgcn_exp2f(rz[i]));
                float z = __builtin_amdgcn_rcpf(1.0f + __builtin_amdgcn_exp2f(rz[4+i]));
                float v = gi + r * gh;
                float n = 1.0f - 2.0f * __builtin_amdgcn_rcpf(__builtin_amdgcn_exp2f(v) + 1.0f);
                hj[t][i] = n + z * (hj[t][i] - n);  // in-place: peers read hjp (old)
            }
        }
    }

    float* op = out + (size_t)row * 7;
    #pragma unroll
    for (int t = 0; t < NJ; ++t) {
        float a = bact[0];
        #pragma unroll
        for (int k = 0; k < HID; ++k) a += Wact[k] * hj[t][k];
        op[t] = a;
    }
}

extern "C" void kernel_launch(void* const* d_in, const int* in_sizes, int n_in,
                              void* d_out, int out_size, void* d_ws, size_t ws_size,
                              hipStream_t stream) {
    const float* x      = (const float*)d_in[0];
    const float* Wj     = (const float*)d_in[1];
    const float* bj     = (const float*)d_in[2];
    const float* Wm     = (const float*)d_in[3];
    const float* bm     = (const float*)d_in[4];
    const float* Wih_j  = (const float*)d_in[5];
    const float* Whh_j  = (const float*)d_in[6];
    const float* bih_j  = (const float*)d_in[7];
    const float* bhh_j  = (const float*)d_in[8];
    const float* Wih_m  = (const float*)d_in[9];
    const float* Whh_m  = (const float*)d_in[10];
    const float* bih_m  = (const float*)d_in[11];
    const float* bhh_m  = (const float*)d_in[12];
    const float* Wact   = (const float*)d_in[13];
    const float* bact   = (const float*)d_in[14];
    float* out = (float*)d_out;
    unsigned int* ws = (unsigned int*)d_ws;

    prep_kernel<<<1, 256, 0, stream>>>(Wih_j, Whh_j, bih_j, bhh_j,
                                       Wih_m, Whh_m, bih_m, bhh_m, ws);

    int B = in_sizes[0] / 19;
    const int block = 256;
    const int grid  = (B + block - 1) / block;
    aggreg_kernel<<<grid, block, 0, stream>>>(
        x, Wj, bj, Wm, bm, Wact, bact, ws, out, B);
}

// Round 10
// 275.512 us; speedup vs baseline: 21.3265x; 2.3763x over previous
//
#include <hip/hip_runtime.h>

typedef __attribute__((ext_vector_type(8))) _Float16 f16x8;
typedef __attribute__((ext_vector_type(4))) float     f32x4;
typedef __attribute__((ext_vector_type(4))) unsigned  u32x4;

#define L2E 1.44269504f

__device__ __forceinline__ unsigned pku(float a, float b) {
    return __builtin_bit_cast(unsigned, __builtin_amdgcn_cvt_pkrtz(a, b));
}
__device__ __forceinline__ float sig2(float s) {  // s pre-scaled by -log2e
    return __builtin_amdgcn_rcpf(1.0f + __builtin_amdgcn_exp2f(s));
}

// ================= ws layout (u32 words) =================
// State ordering: s = i*8 + u  (i = hidden 0..3, u = unit block: 0=hm, 1..7=hj[0..6])
// Gate-row ordering within unit block: m = i*4 + c, c in {0:r, 1:z, 2:gi_n, 3:gh_n}
// [0..2047]     A-frags:  ub*256 + lane*4 + w   f16-pair (k = L4*8+2w, +1) of row m=Ln
// [2048..2175]  C bias:   ub*16 + m  (f32)      (rz biases *-log2e, n biases *2log2e)
// [2176..2687]  init A:   b*256 + lane*4 + w    W_init rows: i=m/4, u=b*4+m%4; k = x index
// [2688..2719]  init C:   b*16 + m  (f32)
// [2720..2724]  Wact[0..3], bact

__global__ __launch_bounds__(256) void prep_kernel(
    const float* __restrict__ Wj,    const float* __restrict__ bj,
    const float* __restrict__ Wm,    const float* __restrict__ bm,
    const float* __restrict__ Wih_j, const float* __restrict__ Whh_j,
    const float* __restrict__ bih_j, const float* __restrict__ bhh_j,
    const float* __restrict__ Wih_m, const float* __restrict__ Whh_m,
    const float* __restrict__ bih_m, const float* __restrict__ bhh_m,
    const float* __restrict__ Wact,  const float* __restrict__ bact,
    unsigned* __restrict__ ws)
{
    int t = blockIdx.x * 256 + threadIdx.x;
    const float c1 = -L2E, c2 = 2.0f * L2E;
    if (t < 2048) {                       // main A-frags
        int ub = t >> 8, rr = t & 255, L = rr >> 2, w = rr & 3;
        int Ln = L & 15, L4 = L >> 4;
        int i = Ln >> 2, c = Ln & 3;
        float vv[2];
        #pragma unroll
        for (int e = 0; e < 2; ++e) {
            int k = L4 * 8 + 2 * w + e;
            int is = k >> 3, us = k & 7;
            float val = 0.0f;
            if (ub == 0) {                // m-unit: x = hj0 (block1), h = hm (block0)
                int g = (c == 0) ? i : (c == 1) ? 4 + i : 8 + i;
                if (c <= 1) {
                    if (us == 1) val += Wih_m[g*4 + is];
                    if (us == 0) val += Whh_m[g*4 + is];
                } else if (c == 2) {
                    if (us == 1) val += Wih_m[g*4 + is];
                } else {
                    if (us == 0) val += Whh_m[g*4 + is];
                }
            } else {                      // joint tj = ub-1
                int tj = ub - 1;
                int lb = (tj == 0) ? 0 : tj;        // left block (hm or hj[tj-1])
                int rb = (tj < 6) ? tj + 2 : -1;    // right block or none
                int g = (c == 0) ? i : (c == 1) ? 4 + i : 8 + i;
                if (c <= 1) {
                    if (us == lb) val += Wih_j[g*8 + is];
                    if (us == rb) val += Wih_j[g*8 + 4 + is];
                    if (us == ub) val += Whh_j[g*4 + is];
                } else if (c == 2) {
                    if (us == lb) val += Wih_j[g*8 + is];
                    if (us == rb) val += Wih_j[g*8 + 4 + is];
                } else {
                    if (us == ub) val += Whh_j[g*4 + is];
                }
            }
            vv[e] = val * ((c <= 1) ? c1 : c2);
        }
        ws[t] = pku(vv[0], vv[1]);
    } else if (t < 2176) {                // C biases
        int tt = t - 2048, ub = tt >> 4, m = tt & 15, i = m >> 2, c = m & 3;
        const float* bi = ub ? bih_j : bih_m;
        const float* bh = ub ? bhh_j : bhh_m;
        float val = (c == 0) ? (bi[i] + bh[i]) * c1
                  : (c == 1) ? (bi[4 + i] + bh[4 + i]) * c1
                  : (c == 2) ? bi[8 + i] * c2
                  :            bh[8 + i] * c2;
        ws[t] = __float_as_uint(val);
    } else if (t < 2688) {                // init A-frags
        int tt = t - 2176, b = tt >> 8, rr = tt & 255, L = rr >> 2, w = rr & 3;
        int Ln = L & 15, L4 = L >> 4;
        int i = Ln >> 2, q = Ln & 3, u = b * 4 + q;
        float vv[2];
        #pragma unroll
        for (int e = 0; e < 2; ++e) {
            int k = L4 * 8 + 2 * w + e;
            float val = 0.0f;
            if (k < 19) {
                if (u == 0) { if (k < 5) val = Wm[i*5 + k]; }
                else {
                    int tj = u - 1;
                    if (k == 5 + tj)       val = Wj[i*2 + 0];
                    else if (k == 12 + tj) val = Wj[i*2 + 1];
                }
            }
            vv[e] = val;
        }
        ws[t] = pku(vv[0], vv[1]);
    } else if (t < 2720) {                // init C
        int tt = t - 2688, b = tt >> 4, m = tt & 15, i = m >> 2, q = m & 3;
        int u = b * 4 + q;
        ws[t] = __float_as_uint(u == 0 ? bm[i] : bj[i]);
    } else if (t < 2724) {
        ws[t] = __float_as_uint(Wact[t - 2720]);
    } else if (t == 2724) {
        ws[t] = __float_as_uint(bact[0]);
    }
}

__global__ __launch_bounds__(256, 3) void aggreg_kernel(
    const float* __restrict__ x, const unsigned* __restrict__ ws,
    float* __restrict__ out)
{
    const int lane = threadIdx.x & 63;
    const int Ln = lane & 15, L4 = lane >> 4;
    const int wave = blockIdx.x * 4 + (threadIdx.x >> 6);
    const long long rowbase = (long long)wave << 6;

    // ---- per-lane weight fragments (VGPR-resident by construction) ----
    f16x8 A[8]; f32x4 C[8];
    #pragma unroll
    for (int u = 0; u < 8; ++u) {
        u32x4 q = *(const u32x4*)(ws + u * 256 + lane * 4);
        A[u] = __builtin_bit_cast(f16x8, q);
        C[u] = *(const f32x4*)((const float*)ws + 2048 + u * 16 + L4 * 4);
    }
    f16x8 IA[2]; f32x4 IC[2];
    #pragma unroll
    for (int b = 0; b < 2; ++b) {
        u32x4 q = *(const u32x4*)(ws + 2176 + b * 256 + lane * 4);
        IA[b] = __builtin_bit_cast(f16x8, q);
        IC[b] = *(const f32x4*)((const float*)ws + 2688 + b * 16 + L4 * 4);
    }

    // ---- init: state = W_init @ x via 2 MFMAs per row-group ----
    float h[4][8];          // h[group][unit] for (row = rowbase+g*16+Ln, hidden = L4)
    unsigned Bf[4][4];      // B-fragments (f16 pairs), lane-local repack of h
    #pragma unroll
    for (int g = 0; g < 4; ++g) {
        long long row = rowbase + g * 16 + Ln;
        const float* xp = x + row * 19;
        float xf[8];
        #pragma unroll
        for (int e = 0; e < 8; ++e) xf[e] = 0.0f;
        if (L4 < 2) {
            #pragma unroll
            for (int e = 0; e < 8; ++e) xf[e] = xp[L4 * 8 + e];
        } else if (L4 == 2) {
            xf[0] = xp[16]; xf[1] = xp[17]; xf[2] = xp[18];
        }
        u32x4 bq;
        bq[0] = pku(xf[0], xf[1]); bq[1] = pku(xf[2], xf[3]);
        bq[2] = pku(xf[4], xf[5]); bq[3] = pku(xf[6], xf[7]);
        f16x8 bxf = __builtin_bit_cast(f16x8, bq);
        f32x4 d0 = __builtin_amdgcn_mfma_f32_16x16x32_f16(IA[0], bxf, IC[0], 0, 0, 0);
        f32x4 d1 = __builtin_amdgcn_mfma_f32_16x16x32_f16(IA[1], bxf, IC[1], 0, 0, 0);
        #pragma unroll
        for (int r = 0; r < 4; ++r) { h[g][r] = d0[r]; h[g][4 + r] = d1[r]; }
        #pragma unroll
        for (int w = 0; w < 4; ++w) Bf[g][w] = pku(h[g][2*w], h[g][2*w+1]);
    }

    // ---- 7 Jacobi iterations: gates = W @ state (MFMA), EW lane-local ----
    for (int it = 0; it < 7; ++it) {
        #pragma unroll
        for (int g = 0; g < 4; ++g) {
            u32x4 bq; bq[0] = Bf[g][0]; bq[1] = Bf[g][1]; bq[2] = Bf[g][2]; bq[3] = Bf[g][3];
            f16x8 bg = __builtin_bit_cast(f16x8, bq);
            #pragma unroll
            for (int u = 0; u < 8; ++u) {
                f32x4 d = __builtin_amdgcn_mfma_f32_16x16x32_f16(A[u], bg, C[u], 0, 0, 0);
                // d[0]=r-pre(-l2e), d[1]=z-pre(-l2e), d[2]=gi_n(2l2e), d[3]=gh_n(2l2e)
                float r  = sig2(d[0]);
                float z  = sig2(d[1]);
                float v  = fmaf(r, d[3], d[2]);
                float nn = 1.0f - 2.0f * __builtin_amdgcn_rcpf(__builtin_amdgcn_exp2f(v) + 1.0f);
                h[g][u] = nn + z * (h[g][u] - nn);   // in-place ok: B stays old until repack
            }
            #pragma unroll
            for (int w = 0; w < 4; ++w) Bf[g][w] = pku(h[g][2*w], h[g][2*w+1]);
        }
    }

    // ---- epilogue: acts = hj @ Wact.T + bact (4-lane butterfly reduce over i) ----
    const float wact = ((const float*)ws)[2720 + L4];
    const float ba   = ((const float*)ws)[2724];
    #pragma unroll
    for (int g = 0; g < 4; ++g) {
        long long row = rowbase + g * 16 + Ln;
        #pragma unroll
        for (int u = 1; u < 8; ++u) {
            float v = wact * h[g][u];
            v += __shfl_xor(v, 16, 64);
            v += __shfl_xor(v, 32, 64);
            if (L4 == 0) out[row * 7 + (u - 1)] = v + ba;
        }
    }
}

extern "C" void kernel_launch(void* const* d_in, const int* in_sizes, int n_in,
                              void* d_out, int out_size, void* d_ws, size_t ws_size,
                              hipStream_t stream) {
    const float* x      = (const float*)d_in[0];
    const float* Wj     = (const float*)d_in[1];
    const float* bj     = (const float*)d_in[2];
    const float* Wm     = (const float*)d_in[3];
    const float* bm     = (const float*)d_in[4];
    const float* Wih_j  = (const float*)d_in[5];
    const float* Whh_j  = (const float*)d_in[6];
    const float* bih_j  = (const float*)d_in[7];
    const float* bhh_j  = (const float*)d_in[8];
    const float* Wih_m  = (const float*)d_in[9];
    const float* Whh_m  = (const float*)d_in[10];
    const float* bih_m  = (const float*)d_in[11];
    const float* bhh_m  = (const float*)d_in[12];
    const float* Wact   = (const float*)d_in[13];
    const float* bact   = (const float*)d_in[14];
    float* out = (float*)d_out;
    unsigned* ws = (unsigned*)d_ws;

    prep_kernel<<<11, 256, 0, stream>>>(Wj, bj, Wm, bm,
                                        Wih_j, Whh_j, bih_j, bhh_j,
                                        Wih_m, Whh_m, bih_m, bhh_m,
                                        Wact, bact, ws);

    int B = in_sizes[0] / 19;        // 2097152 rows, exact multiple of 256
    int grid = B / 256;              // 256 rows per block (4 waves x 64 rows)
    aggreg_kernel<<<grid, 256, 0, stream>>>(x, ws, out);
}

// Round 11
// 273.445 us; speedup vs baseline: 21.4878x; 1.0076x over previous
//
#include <hip/hip_runtime.h>

typedef __attribute__((ext_vector_type(8))) _Float16 f16x8;
typedef __attribute__((ext_vector_type(4))) float     f32x4;
typedef __attribute__((ext_vector_type(4))) unsigned  u32x4;

#define L2E 1.44269504f

__device__ __forceinline__ unsigned pku(float a, float b) {
    return __builtin_bit_cast(unsigned, __builtin_amdgcn_cvt_pkrtz(a, b));
}
__device__ __forceinline__ float sig2(float s) {  // s pre-scaled by -log2e
    return __builtin_amdgcn_rcpf(1.0f + __builtin_amdgcn_exp2f(s));
}

// ================= ws layout (u32 words) =================
// State ordering: s = i*8 + u  (i = hidden 0..3, u = unit block: 0=hm, 1..7=hj[0..6])
// Gate-row ordering within unit block: m = i*4 + c, c in {0:r, 1:z, 2:gi_n, 3:gh_n}
// [0..2047]     A-frags:  ub*256 + lane*4 + w   f16-pair (k = L4*8+2w, +1) of row m=Ln
// [2048..2175]  C bias:   ub*16 + m  (f32)      (rz biases *-log2e, n biases *2log2e)
// [2176..2687]  init A:   b*256 + lane*4 + w    W_init rows: i=m/4, u=b*4+m%4; k = x index
// [2688..2719]  init C:   b*16 + m  (f32)
// [2720..2724]  Wact[0..3], bact

__global__ __launch_bounds__(256) void prep_kernel(
    const float* __restrict__ Wj,    const float* __restrict__ bj,
    const float* __restrict__ Wm,    const float* __restrict__ bm,
    const float* __restrict__ Wih_j, const float* __restrict__ Whh_j,
    const float* __restrict__ bih_j, const float* __restrict__ bhh_j,
    const float* __restrict__ Wih_m, const float* __restrict__ Whh_m,
    const float* __restrict__ bih_m, const float* __restrict__ bhh_m,
    const float* __restrict__ Wact,  const float* __restrict__ bact,
    unsigned* __restrict__ ws)
{
    int t = blockIdx.x * 256 + threadIdx.x;
    const float c1 = -L2E, c2 = 2.0f * L2E;
    if (t < 2048) {                       // main A-frags
        int ub = t >> 8, rr = t & 255, L = rr >> 2, w = rr & 3;
        int Ln = L & 15, L4 = L >> 4;
        int i = Ln >> 2, c = Ln & 3;
        float vv[2];
        #pragma unroll
        for (int e = 0; e < 2; ++e) {
            int k = L4 * 8 + 2 * w + e;
            int is = k >> 3, us = k & 7;
            float val = 0.0f;
            if (ub == 0) {                // m-unit: x = hj0 (block1), h = hm (block0)
                int g = (c == 0) ? i : (c == 1) ? 4 + i : 8 + i;
                if (c <= 1) {
                    if (us == 1) val += Wih_m[g*4 + is];
                    if (us == 0) val += Whh_m[g*4 + is];
                } else if (c == 2) {
                    if (us == 1) val += Wih_m[g*4 + is];
                } else {
                    if (us == 0) val += Whh_m[g*4 + is];
                }
            } else {                      // joint tj = ub-1
                int tj = ub - 1;
                int lb = (tj == 0) ? 0 : tj;        // left block (hm or hj[tj-1])
                int rb = (tj < 6) ? tj + 2 : -1;    // right block or none
                int g = (c == 0) ? i : (c == 1) ? 4 + i : 8 + i;
                if (c <= 1) {
                    if (us == lb) val += Wih_j[g*8 + is];
                    if (us == rb) val += Wih_j[g*8 + 4 + is];
                    if (us == ub) val += Whh_j[g*4 + is];
                } else if (c == 2) {
                    if (us == lb) val += Wih_j[g*8 + is];
                    if (us == rb) val += Wih_j[g*8 + 4 + is];
                } else {
                    if (us == ub) val += Whh_j[g*4 + is];
                }
            }
            vv[e] = val * ((c <= 1) ? c1 : c2);
        }
        ws[t] = pku(vv[0], vv[1]);
    } else if (t < 2176) {                // C biases
        int tt = t - 2048, ub = tt >> 4, m = tt & 15, i = m >> 2, c = m & 3;
        const float* bi = ub ? bih_j : bih_m;
        const float* bh = ub ? bhh_j : bhh_m;
        float val = (c == 0) ? (bi[i] + bh[i]) * c1
                  : (c == 1) ? (bi[4 + i] + bh[4 + i]) * c1
                  : (c == 2) ? bi[8 + i] * c2
                  :            bh[8 + i] * c2;
        ws[t] = __float_as_uint(val);
    } else if (t < 2688) {                // init A-frags
        int tt = t - 2176, b = tt >> 8, rr = tt & 255, L = rr >> 2, w = rr & 3;
        int Ln = L & 15, L4 = L >> 4;
        int i = Ln >> 2, q = Ln & 3, u = b * 4 + q;
        float vv[2];
        #pragma unroll
        for (int e = 0; e < 2; ++e) {
            int k = L4 * 8 + 2 * w + e;
            float val = 0.0f;
            if (k < 19) {
                if (u == 0) { if (k < 5) val = Wm[i*5 + k]; }
                else {
                    int tj = u - 1;
                    if (k == 5 + tj)       val = Wj[i*2 + 0];
                    else if (k == 12 + tj) val = Wj[i*2 + 1];
                }
            }
            vv[e] = val;
        }
        ws[t] = pku(vv[0], vv[1]);
    } else if (t < 2720) {                // init C
        int tt = t - 2688, b = tt >> 4, m = tt & 15, i = m >> 2, q = m & 3;
        int u = b * 4 + q;
        ws[t] = __float_as_uint(u == 0 ? bm[i] : bj[i]);
    } else if (t < 2724) {
        ws[t] = __float_as_uint(Wact[t - 2720]);
    } else if (t == 2724) {
        ws[t] = __float_as_uint(bact[0]);
    }
}

__global__ __launch_bounds__(256, 3) void aggreg_kernel(
    const float* __restrict__ x, const unsigned* __restrict__ ws,
    float* __restrict__ out)
{
    const int lane = threadIdx.x & 63;
    const int Ln = lane & 15, L4 = lane >> 4;
    const int wave = blockIdx.x * 4 + (threadIdx.x >> 6);
    const long long rowbase = (long long)wave << 6;

    // ---- stage weight table (A-frags + C biases, 8.7 KB) into LDS: the LDS
    //      pipe is idle, ds_read ~6cy vs ~150cy L1/L2 reload the compiler was
    //      emitting (VGPR=68 < the 64 regs A/C need => it remats per use) ----
    __shared__ unsigned sh[2176];
    for (int i = threadIdx.x; i < 2176; i += 256) sh[i] = ws[i];
    __syncthreads();

    // ---- init: state = W_init @ x via 2 MFMAs per row-group ----
    f16x8 IA[2]; f32x4 IC[2];
    #pragma unroll
    for (int b = 0; b < 2; ++b) {
        u32x4 q = *(const u32x4*)(ws + 2176 + b * 256 + lane * 4);
        IA[b] = __builtin_bit_cast(f16x8, q);
        IC[b] = *(const f32x4*)((const float*)ws + 2688 + b * 16 + L4 * 4);
    }
    float h[4][8];          // h[group][unit] for (row = rowbase+g*16+Ln, hidden = L4)
    unsigned Bf[4][4];      // B-fragments (f16 pairs), lane-local repack of h
    #pragma unroll
    for (int g = 0; g < 4; ++g) {
        long long row = rowbase + g * 16 + Ln;
        const float* xp = x + row * 19;
        float xf[8];
        #pragma unroll
        for (int e = 0; e < 8; ++e) xf[e] = 0.0f;
        if (L4 < 2) {
            #pragma unroll
            for (int e = 0; e < 8; ++e) xf[e] = xp[L4 * 8 + e];
        } else if (L4 == 2) {
            xf[0] = xp[16]; xf[1] = xp[17]; xf[2] = xp[18];
        }
        u32x4 bq;
        bq[0] = pku(xf[0], xf[1]); bq[1] = pku(xf[2], xf[3]);
        bq[2] = pku(xf[4], xf[5]); bq[3] = pku(xf[6], xf[7]);
        f16x8 bxf = __builtin_bit_cast(f16x8, bq);
        f32x4 d0 = __builtin_amdgcn_mfma_f32_16x16x32_f16(IA[0], bxf, IC[0], 0, 0, 0);
        f32x4 d1 = __builtin_amdgcn_mfma_f32_16x16x32_f16(IA[1], bxf, IC[1], 0, 0, 0);
        #pragma unroll
        for (int r = 0; r < 4; ++r) { h[g][r] = d0[r]; h[g][4 + r] = d1[r]; }
        #pragma unroll
        for (int w = 0; w < 4; ++w) Bf[g][w] = pku(h[g][2*w], h[g][2*w+1]);
    }

    // ---- 7 Jacobi iterations: gates = W @ state (MFMA), EW lane-local ----
    for (int it = 0; it < 7; ++it) {
        #pragma unroll
        for (int g = 0; g < 4; ++g) {
            if (it > 0) {   // repack at iteration start (skips the dead final repack)
                #pragma unroll
                for (int w = 0; w < 4; ++w) Bf[g][w] = pku(h[g][2*w], h[g][2*w+1]);
            }
            u32x4 bq; bq[0] = Bf[g][0]; bq[1] = Bf[g][1]; bq[2] = Bf[g][2]; bq[3] = Bf[g][3];
            f16x8 bg = __builtin_bit_cast(f16x8, bq);
            #pragma unroll
            for (int u = 0; u < 8; ++u) {
                if (u == 0 && it == 6) continue;   // h_m dead after last iteration
                u32x4 aq = *(const u32x4*)(sh + u * 256 + lane * 4);
                f16x8 Au = __builtin_bit_cast(f16x8, aq);
                f32x4 Cu = *(const f32x4*)((const float*)sh + 2048 + u * 16 + L4 * 4);
                f32x4 d = __builtin_amdgcn_mfma_f32_16x16x32_f16(Au, bg, Cu, 0, 0, 0);
                // d[0]=r-pre(-l2e), d[1]=z-pre(-l2e), d[2]=gi_n(2l2e), d[3]=gh_n(2l2e)
                float r  = sig2(d[0]);
                float z  = sig2(d[1]);
                float v  = fmaf(r, d[3], d[2]);
                float nn = 1.0f - 2.0f * __builtin_amdgcn_rcpf(__builtin_amdgcn_exp2f(v) + 1.0f);
                h[g][u] = nn + z * (h[g][u] - nn);   // in-place ok: B stays old until repack
            }
        }
    }

    // ---- epilogue: acts = hj @ Wact.T + bact (butterfly reduce over hidden i) ----
    const float wact = ((const float*)ws)[2720 + L4];
    const float ba   = ((const float*)ws)[2724];
    #pragma unroll
    for (int g = 0; g < 4; ++g) {
        long long row = rowbase + g * 16 + Ln;
        #pragma unroll
        for (int u = 1; u < 8; ++u) {
            float v = wact * h[g][u];
            v += __shfl_xor(v, 16, 64);
            v += __shfl_xor(v, 32, 64);
            if (L4 == 0) out[row * 7 + (u - 1)] = v + ba;
        }
    }
}

extern "C" void kernel_launch(void* const* d_in, const int* in_sizes, int n_in,
                              void* d_out, int out_size, void* d_ws, size_t ws_size,
                              hipStream_t stream) {
    const float* x      = (const float*)d_in[0];
    const float* Wj     = (const float*)d_in[1];
    const float* bj     = (const float*)d_in[2];
    const float* Wm     = (const float*)d_in[3];
    const float* bm     = (const float*)d_in[4];
    const float* Wih_j  = (const float*)d_in[5];
    const float* Whh_j  = (const float*)d_in[6];
    const float* bih_j  = (const float*)d_in[7];
    const float* bhh_j  = (const float*)d_in[8];
    const float* Wih_m  = (const float*)d_in[9];
    const float* Whh_m  = (const float*)d_in[10];
    const float* bih_m  = (const float*)d_in[11];
    const float* bhh_m  = (const float*)d_in[12];
    const float* Wact   = (const float*)d_in[13];
    const float* bact   = (const float*)d_in[14];
    float* out = (float*)d_out;
    unsigned* ws = (unsigned*)d_ws;

    prep_kernel<<<11, 256, 0, stream>>>(Wj, bj, Wm, bm,
                                        Wih_j, Whh_j, bih_j, bhh_j,
                                        Wih_m, Whh_m, bih_m, bhh_m,
                                        Wact, bact, ws);

    int B = in_sizes[0] / 19;        // 2097152 rows, exact multiple of 256
    int grid = B / 256;              // 256 rows per block (4 waves x 64 rows)
    aggreg_kernel<<<grid, 256, 0, stream>>>(x, ws, out);
}